// Round 1
// baseline (610.202 us; speedup 1.0000x reference)
//
#include <hip/hip_runtime.h>
#include <math.h>

// Problem constants
#define B_    256
#define T_    2048
#define DIN   64
#define H_    32
#define C_    16

// Time-chunking: chunk length 256, burn-in 96 (state forgets init at rate
// <= ||W_res_masked|| ~ 0.6/step; 0.9^96 ~ 4e-5 worst case vs 2.3e-2 threshold)
#define CHUNK 256
#define WARM  96
#define NCHUNK (T_ / CHUNK)   // 8

// Workspace layout (bytes). Needs ~129 MB total.
#define OFF_WCOMB 0u
#define OFF_BCOMB 4096u
#define OFF_U     (1u << 20)                      // u_enc: [B,T,H] fp32 = 64 MiB
#define OFF_DEC   ((1u << 20) + (64u << 20))      // dec states: [B,T,H] fp32 = 64 MiB

__device__ __forceinline__ float fast_tanh(float x) {
    // tanh(x) = 1 - 2/(e^{2x}+1); saturates correctly at +/-inf, no NaN.
    float e2 = __expf(x + x);
    return 1.0f - 2.0f * __builtin_amdgcn_rcpf(e2 + 1.0f);
}

// ---------------------------------------------------------------------------
// Prep: W_comb = W_co @ W_code  (H x H), b_comb = W_co @ b_code + b_co
// ---------------------------------------------------------------------------
__global__ __launch_bounds__(1024) void prep_kernel(
        const float* __restrict__ W_code, const float* __restrict__ b_code,
        const float* __restrict__ W_co,   const float* __restrict__ b_co,
        float* __restrict__ W_comb, float* __restrict__ b_comb) {
    int t = threadIdx.x;           // 1024 threads = 32x32 outputs
    int i = t >> 5, j = t & 31;
    float s = 0.0f;
#pragma unroll
    for (int c = 0; c < C_; ++c)
        s += W_co[i * C_ + c] * W_code[c * H_ + j];
    W_comb[i * H_ + j] = s;
    if (t < H_) {
        float sb = b_co[t];
#pragma unroll
        for (int c = 0; c < C_; ++c)
            sb += W_co[t * C_ + c] * b_code[c];
        b_comb[t] = sb;
    }
}

// ---------------------------------------------------------------------------
// k1: u[b,t,h] = sum_d x[b,t,d] * W_in[h,d] + b_in[h]
// Thread handles 4 consecutive rows; W_in broadcast from LDS (reused across
// the 4 rows -> 16 FMA per ds_read_b128). Memory-bound target ~200 MB.
// ---------------------------------------------------------------------------
__global__ __launch_bounds__(256) void inproj_kernel(
        const float* __restrict__ x, const float* __restrict__ W_in,
        const float* __restrict__ b_in, float* __restrict__ u) {
    __shared__ __align__(16) float lw[H_ * DIN];
    __shared__ float lb[H_];
    for (int v = threadIdx.x; v < H_ * DIN; v += 256) lw[v] = W_in[v];
    if (threadIdx.x < H_) lb[threadIdx.x] = b_in[threadIdx.x];
    __syncthreads();

    long row0 = (long)(blockIdx.x * 256 + threadIdx.x) * 4;
    const float4* xr0 = reinterpret_cast<const float4*>(x + row0 * DIN);
    const float4* xr1 = reinterpret_cast<const float4*>(x + (row0 + 1) * DIN);
    const float4* xr2 = reinterpret_cast<const float4*>(x + (row0 + 2) * DIN);
    const float4* xr3 = reinterpret_cast<const float4*>(x + (row0 + 3) * DIN);
    const float4* lw4 = reinterpret_cast<const float4*>(lw);

    float acc[4][H_];
#pragma unroll
    for (int r = 0; r < 4; ++r)
#pragma unroll
        for (int i = 0; i < H_; ++i) acc[r][i] = 0.0f;

    for (int k4 = 0; k4 < DIN / 4; ++k4) {
        float4 xv0 = xr0[k4], xv1 = xr1[k4], xv2 = xr2[k4], xv3 = xr3[k4];
#pragma unroll
        for (int i = 0; i < H_; ++i) {
            float4 w = lw4[i * (DIN / 4) + k4];
            acc[0][i] += xv0.x * w.x + xv0.y * w.y + xv0.z * w.z + xv0.w * w.w;
            acc[1][i] += xv1.x * w.x + xv1.y * w.y + xv1.z * w.z + xv1.w * w.w;
            acc[2][i] += xv2.x * w.x + xv2.y * w.y + xv2.z * w.z + xv2.w * w.w;
            acc[3][i] += xv3.x * w.x + xv3.y * w.y + xv3.z * w.z + xv3.w * w.w;
        }
    }
#pragma unroll
    for (int r = 0; r < 4; ++r) {
        float4* ur = reinterpret_cast<float4*>(u + (row0 + r) * H_);
#pragma unroll
        for (int q = 0; q < H_ / 4; ++q) {
            float4 o;
            o.x = acc[r][4 * q + 0] + lb[4 * q + 0];
            o.y = acc[r][4 * q + 1] + lb[4 * q + 1];
            o.z = acc[r][4 * q + 2] + lb[4 * q + 2];
            o.w = acc[r][4 * q + 3] + lb[4 * q + 3];
            ur[q] = o;
        }
    }
}

// ---------------------------------------------------------------------------
// k2: fused enc-scan -> (code+decode = W_comb) -> dec-scan, time-chunked with
// burn-in. One wave (64 threads) per block; lanes 0-31 = batch b0, 32-63 = b1,
// both halves on the SAME chunk (uniform loop). State replicated per lane in
// VGPRs (matvec = 32 local FMAs); per-step allgather of 32 new values via LDS
// (ds_write_b32 + 8x ds_read_b128 broadcast). Single-wave block -> no barrier
// needed; in-wave DS ordering + lgkmcnt handles the RAW.
// ---------------------------------------------------------------------------
__global__ __launch_bounds__(64) void scan_kernel(
        const float* __restrict__ u,
        const float* __restrict__ W_res_enc, const float* __restrict__ b_res_enc,
        const float* __restrict__ W_res_dec, const float* __restrict__ b_res_dec,
        const float* __restrict__ W_comb,    const float* __restrict__ b_comb,
        float* __restrict__ dec) {
    int lane = threadIdx.x;
    int i = lane & 31;
    int half = lane >> 5;
    int b  = ((blockIdx.x & 127) << 1) | half;   // both halves share chunk c
    int c  = blockIdx.x >> 7;                    // 0..7
    int t0 = c * CHUNK;
    int tstart = (c == 0) ? 0 : (t0 - WARM);
    int tend = t0 + CHUNK;

    // Per-lane weight rows (row i of each matrix), via float4 loads.
    float We[H_], Wc[H_], Wd[H_];
    {
        const float4* we4 = reinterpret_cast<const float4*>(W_res_enc + i * H_);
        const float4* wc4 = reinterpret_cast<const float4*>(W_comb + i * H_);
        const float4* wd4 = reinterpret_cast<const float4*>(W_res_dec + i * H_);
#pragma unroll
        for (int q = 0; q < H_ / 4; ++q) {
            float4 a = we4[q], bq = wc4[q], d = wd4[q];
            We[4*q+0] = a.x;  We[4*q+1] = a.y;  We[4*q+2] = a.z;  We[4*q+3] = a.w;
            Wc[4*q+0] = bq.x; Wc[4*q+1] = bq.y; Wc[4*q+2] = bq.z; Wc[4*q+3] = bq.w;
            Wd[4*q+0] = d.x;  Wd[4*q+1] = d.y;  Wd[4*q+2] = d.z;  Wd[4*q+3] = d.w;
        }
    }
    float be = b_res_enc[i], bc = b_comb[i], bd = b_res_dec[i];

    float henc[H_], hdec[H_];
#pragma unroll
    for (int j = 0; j < H_; ++j) { henc[j] = 0.0f; hdec[j] = 0.0f; }

    __shared__ __align__(16) float lhe[2][H_];
    __shared__ __align__(16) float lhd[2][H_];

    const float* ub = u + ((long)b * T_) * H_ + i;
    float*       db = dec + ((long)b * T_) * H_ + i;

    float ucur = ub[(long)tstart * H_];
    for (int t = tstart; t < tend; ++t) {
        float unext = 0.0f;
        if (t + 1 < tend) unext = ub[(long)(t + 1) * H_];

        // encoder update: a = tanh(u + We . henc + be)
        float a = ucur + be;
#pragma unroll
        for (int j = 0; j < H_; ++j) a += We[j] * henc[j];
        a = fast_tanh(a);

        lhe[half][i] = a;
#pragma unroll
        for (int q = 0; q < H_ / 4; ++q) {
            float4 v = *reinterpret_cast<const float4*>(&lhe[half][4 * q]);
            henc[4*q+0] = v.x; henc[4*q+1] = v.y;
            henc[4*q+2] = v.z; henc[4*q+3] = v.w;
        }

        // fused code+decode input: g = W_comb . henc + b_comb
        float g = bc;
#pragma unroll
        for (int j = 0; j < H_; ++j) g += Wc[j] * henc[j];

        // decoder update: d = tanh(g + Wd . hdec + bd)
        float d = g + bd;
#pragma unroll
        for (int j = 0; j < H_; ++j) d += Wd[j] * hdec[j];
        d = fast_tanh(d);

        lhd[half][i] = d;
#pragma unroll
        for (int q = 0; q < H_ / 4; ++q) {
            float4 v = *reinterpret_cast<const float4*>(&lhd[half][4 * q]);
            hdec[4*q+0] = v.x; hdec[4*q+1] = v.y;
            hdec[4*q+2] = v.z; hdec[4*q+3] = v.w;
        }

        if (t >= t0) db[(long)t * H_] = d;
        ucur = unext;
    }
}

// ---------------------------------------------------------------------------
// k3: out[b,t,d] = sum_i dec[b,t,i] * W_ro[d,i] + b_ro[d]
// Thread handles 2 rows; W_ro broadcast from LDS.
// ---------------------------------------------------------------------------
__global__ __launch_bounds__(256) void readout_kernel(
        const float* __restrict__ dec, const float* __restrict__ W_ro,
        const float* __restrict__ b_ro, float* __restrict__ out) {
    __shared__ __align__(16) float lw[DIN * H_];
    __shared__ float lb[DIN];
    for (int v = threadIdx.x; v < DIN * H_; v += 256) lw[v] = W_ro[v];
    if (threadIdx.x < DIN) lb[threadIdx.x] = b_ro[threadIdx.x];
    __syncthreads();

    long row0 = (long)(blockIdx.x * 256 + threadIdx.x) * 2;
    const float4* d0 = reinterpret_cast<const float4*>(dec + row0 * H_);
    const float4* d1 = reinterpret_cast<const float4*>(dec + (row0 + 1) * H_);
    const float4* lw4 = reinterpret_cast<const float4*>(lw);

    float acc[2][DIN];
#pragma unroll
    for (int r = 0; r < 2; ++r)
#pragma unroll
        for (int i = 0; i < DIN; ++i) acc[r][i] = 0.0f;

    for (int k4 = 0; k4 < H_ / 4; ++k4) {
        float4 xv0 = d0[k4], xv1 = d1[k4];
#pragma unroll
        for (int i = 0; i < DIN; ++i) {
            float4 w = lw4[i * (H_ / 4) + k4];
            acc[0][i] += xv0.x * w.x + xv0.y * w.y + xv0.z * w.z + xv0.w * w.w;
            acc[1][i] += xv1.x * w.x + xv1.y * w.y + xv1.z * w.z + xv1.w * w.w;
        }
    }
#pragma unroll
    for (int r = 0; r < 2; ++r) {
        float4* orow = reinterpret_cast<float4*>(out + (row0 + r) * DIN);
#pragma unroll
        for (int q = 0; q < DIN / 4; ++q) {
            float4 o;
            o.x = acc[r][4 * q + 0] + lb[4 * q + 0];
            o.y = acc[r][4 * q + 1] + lb[4 * q + 1];
            o.z = acc[r][4 * q + 2] + lb[4 * q + 2];
            o.w = acc[r][4 * q + 3] + lb[4 * q + 3];
            orow[q] = o;
        }
    }
}

extern "C" void kernel_launch(void* const* d_in, const int* in_sizes, int n_in,
                              void* d_out, int out_size, void* d_ws, size_t ws_size,
                              hipStream_t stream) {
    const float* x         = (const float*)d_in[0];
    const float* W_in      = (const float*)d_in[1];
    const float* b_in      = (const float*)d_in[2];
    const float* W_res_enc = (const float*)d_in[3];
    const float* b_res_enc = (const float*)d_in[4];
    const float* W_code    = (const float*)d_in[5];
    const float* b_code    = (const float*)d_in[6];
    const float* W_co      = (const float*)d_in[7];
    const float* b_co      = (const float*)d_in[8];
    const float* W_res_dec = (const float*)d_in[9];
    const float* b_res_dec = (const float*)d_in[10];
    const float* W_ro      = (const float*)d_in[11];
    const float* b_ro      = (const float*)d_in[12];
    float* out = (float*)d_out;

    char* ws = (char*)d_ws;
    float* W_comb = (float*)(ws + OFF_WCOMB);
    float* b_comb = (float*)(ws + OFF_BCOMB);
    float* u      = (float*)(ws + OFF_U);
    float* decs   = (float*)(ws + OFF_DEC);

    prep_kernel<<<1, 1024, 0, stream>>>(W_code, b_code, W_co, b_co, W_comb, b_comb);
    inproj_kernel<<<(B_ * T_) / (256 * 4), 256, 0, stream>>>(x, W_in, b_in, u);
    scan_kernel<<<(B_ / 2) * NCHUNK, 64, 0, stream>>>(u, W_res_enc, b_res_enc,
                                                      W_res_dec, b_res_dec,
                                                      W_comb, b_comb, decs);
    readout_kernel<<<(B_ * T_) / (256 * 2), 256, 0, stream>>>(decs, W_ro, b_ro, out);
}

// Round 2
// 508.031 us; speedup vs baseline: 1.2011x; 1.2011x over previous
//
#include <hip/hip_runtime.h>
#include <math.h>

// Problem constants
#define B_    256
#define T_    2048
#define DIN   64
#define H_    32
#define C_    16

// Time-chunking: chunk length 256, burn-in 96.
#define CHUNK 256
#define WARM  96
#define NCHUNK (T_ / CHUNK)   // 8

// Workspace layout (bytes).
#define OFF_WCOMB 0u
#define OFF_BCOMB 4096u
#define OFF_U     (1u << 20)   // u_enc: [B*T, H] fp32 = 64 MiB

__device__ __forceinline__ float fast_tanh(float x) {
    float e2 = __expf(x + x);
    return 1.0f - 2.0f * __builtin_amdgcn_rcpf(e2 + 1.0f);
}

// ---------------------------------------------------------------------------
// Prep: W_comb = W_co @ W_code  (H x H), b_comb = W_co @ b_code + b_co
// ---------------------------------------------------------------------------
__global__ __launch_bounds__(1024) void prep_kernel(
        const float* __restrict__ W_code, const float* __restrict__ b_code,
        const float* __restrict__ W_co,   const float* __restrict__ b_co,
        float* __restrict__ W_comb, float* __restrict__ b_comb) {
    int t = threadIdx.x;
    int i = t >> 5, j = t & 31;
    float s = 0.0f;
#pragma unroll
    for (int c = 0; c < C_; ++c)
        s += W_co[i * C_ + c] * W_code[c * H_ + j];
    W_comb[i * H_ + j] = s;
    if (t < H_) {
        float sb = b_co[t];
#pragma unroll
        for (int c = 0; c < C_; ++c)
            sb += W_co[t * C_ + c] * b_code[c];
        b_comb[t] = sb;
    }
}

// ---------------------------------------------------------------------------
// k1: u[r,i] = sum_d x[r,d]*W_in[i,d] + b_in[i],  r = b*T+t  (coalesced)
// 128-row x tile staged in LDS via coalesced float4 loads. W_in row i lives
// in VGPRs (64 regs/lane). Wave w computes rows [w*32, w*32+32): lane
// (i=lane&31, par=lane>>5) handles rows {g*8+par+2j} — LDS reads are
// 2-address broadcasts (cheap), stores are 128B-per-half coalesced.
// ---------------------------------------------------------------------------
__global__ __launch_bounds__(256) void inproj_kernel(
        const float* __restrict__ x, const float* __restrict__ W_in,
        const float* __restrict__ b_in, float* __restrict__ u) {
    __shared__ __align__(16) float4 lx[128 * 16];   // 32 KiB: [row][k4]

    int tid  = threadIdx.x;
    int w    = tid >> 6;
    int lane = tid & 63;
    int i    = lane & 31;
    int par  = lane >> 5;

    // W_in row i -> registers (redundant across halves; L2-resident)
    float Wr[DIN];
    {
        const float4* wi4 = reinterpret_cast<const float4*>(W_in + i * DIN);
#pragma unroll
        for (int q = 0; q < DIN / 4; ++q) {
            float4 v = wi4[q];
            Wr[4*q+0] = v.x; Wr[4*q+1] = v.y; Wr[4*q+2] = v.z; Wr[4*q+3] = v.w;
        }
    }
    float bi = b_in[i];

    long row_base = (long)blockIdx.x * 128;
    const float4* xg = reinterpret_cast<const float4*>(x) + row_base * 16;

    // stage tile: 2048 float4, 256 threads -> 8 each, coalesced
#pragma unroll
    for (int k = 0; k < 8; ++k)
        lx[tid + 256 * k] = xg[tid + 256 * k];
    __syncthreads();

#pragma unroll
    for (int g = 0; g < 4; ++g) {
        int r0 = w * 32 + g * 8 + par;      // rows r0, r0+2, r0+4, r0+6
        float acc0 = 0.f, acc1 = 0.f, acc2 = 0.f, acc3 = 0.f;
#pragma unroll
        for (int k4 = 0; k4 < 16; ++k4) {
            float4 wv = { Wr[4*k4+0], Wr[4*k4+1], Wr[4*k4+2], Wr[4*k4+3] };
            float4 x0 = lx[(r0 + 0) * 16 + k4];
            float4 x1 = lx[(r0 + 2) * 16 + k4];
            float4 x2 = lx[(r0 + 4) * 16 + k4];
            float4 x3 = lx[(r0 + 6) * 16 + k4];
            acc0 += x0.x * wv.x + x0.y * wv.y + x0.z * wv.z + x0.w * wv.w;
            acc1 += x1.x * wv.x + x1.y * wv.y + x1.z * wv.z + x1.w * wv.w;
            acc2 += x2.x * wv.x + x2.y * wv.y + x2.z * wv.z + x2.w * wv.w;
            acc3 += x3.x * wv.x + x3.y * wv.y + x3.z * wv.z + x3.w * wv.w;
        }
        long rg = row_base + r0;
        u[(rg + 0) * H_ + i] = acc0 + bi;
        u[(rg + 2) * H_ + i] = acc1 + bi;
        u[(rg + 4) * H_ + i] = acc2 + bi;
        u[(rg + 6) * H_ + i] = acc3 + bi;
    }
}

// ---------------------------------------------------------------------------
// k2: fused enc-scan -> W_comb -> dec-scan -> READOUT, time-chunked w/ burn-in.
// One wave per block, lanes 0-31 = batch b0, 32-63 = b1 (same chunk).
// States replicated per lane; per-step allgather via LDS broadcast.
// Readout W_ro rows 2i,2i+1 in VGPRs; out written as coalesced float2.
// ---------------------------------------------------------------------------
__global__ __launch_bounds__(64, 1) void scan_kernel(
        const float* __restrict__ u,
        const float* __restrict__ W_res_enc, const float* __restrict__ b_res_enc,
        const float* __restrict__ W_res_dec, const float* __restrict__ b_res_dec,
        const float* __restrict__ W_comb,    const float* __restrict__ b_comb,
        const float* __restrict__ W_ro,      const float* __restrict__ b_ro,
        float* __restrict__ out) {
    int lane = threadIdx.x;
    int i = lane & 31;
    int half = lane >> 5;
    int b  = ((blockIdx.x & 127) << 1) | half;
    int c  = blockIdx.x >> 7;
    int t0 = c * CHUNK;
    int tstart = (c == 0) ? 0 : (t0 - WARM);
    int tend = t0 + CHUNK;

    float We[H_], Wc[H_], Wd[H_], Wo0[H_], Wo1[H_];
    {
        const float4* we4 = reinterpret_cast<const float4*>(W_res_enc + i * H_);
        const float4* wc4 = reinterpret_cast<const float4*>(W_comb + i * H_);
        const float4* wd4 = reinterpret_cast<const float4*>(W_res_dec + i * H_);
        const float4* wo0 = reinterpret_cast<const float4*>(W_ro + (2 * i) * H_);
        const float4* wo1 = reinterpret_cast<const float4*>(W_ro + (2 * i + 1) * H_);
#pragma unroll
        for (int q = 0; q < H_ / 4; ++q) {
            float4 a = we4[q], bq = wc4[q], d = wd4[q], o0 = wo0[q], o1 = wo1[q];
            We[4*q+0]=a.x;  We[4*q+1]=a.y;  We[4*q+2]=a.z;  We[4*q+3]=a.w;
            Wc[4*q+0]=bq.x; Wc[4*q+1]=bq.y; Wc[4*q+2]=bq.z; Wc[4*q+3]=bq.w;
            Wd[4*q+0]=d.x;  Wd[4*q+1]=d.y;  Wd[4*q+2]=d.z;  Wd[4*q+3]=d.w;
            Wo0[4*q+0]=o0.x;Wo0[4*q+1]=o0.y;Wo0[4*q+2]=o0.z;Wo0[4*q+3]=o0.w;
            Wo1[4*q+0]=o1.x;Wo1[4*q+1]=o1.y;Wo1[4*q+2]=o1.z;Wo1[4*q+3]=o1.w;
        }
    }
    float be = b_res_enc[i], bc = b_comb[i], bd = b_res_dec[i];
    float bo0 = b_ro[2 * i], bo1 = b_ro[2 * i + 1];

    float henc[H_], hdec[H_];
#pragma unroll
    for (int j = 0; j < H_; ++j) { henc[j] = 0.0f; hdec[j] = 0.0f; }

    __shared__ __align__(16) float lhe[2][H_];
    __shared__ __align__(16) float lhd[2][H_];

    const float* ub = u + ((long)b * T_) * H_ + i;
    float*       ob = out + ((long)b * T_) * DIN + 2 * i;

    float ucur = ub[(long)tstart * H_];
    for (int t = tstart; t < tend; ++t) {
        float unext = 0.0f;
        if (t + 1 < tend) unext = ub[(long)(t + 1) * H_];

        // encoder: a = tanh(u + We.henc + be)  (4-acc tree)
        float a0 = ucur + be, a1 = 0.f, a2 = 0.f, a3 = 0.f;
#pragma unroll
        for (int j = 0; j < H_; j += 4) {
            a0 += We[j+0] * henc[j+0];
            a1 += We[j+1] * henc[j+1];
            a2 += We[j+2] * henc[j+2];
            a3 += We[j+3] * henc[j+3];
        }
        float a = fast_tanh((a0 + a1) + (a2 + a3));

        lhe[half][i] = a;
#pragma unroll
        for (int q = 0; q < H_ / 4; ++q) {
            float4 v = *reinterpret_cast<const float4*>(&lhe[half][4 * q]);
            henc[4*q+0] = v.x; henc[4*q+1] = v.y;
            henc[4*q+2] = v.z; henc[4*q+3] = v.w;
        }

        // fused code+decode: g = Wc.henc + bc ; decoder: d = tanh(g + Wd.hdec + bd)
        float g0 = bc + bd, g1 = 0.f, g2 = 0.f, g3 = 0.f;
#pragma unroll
        for (int j = 0; j < H_; j += 4) {
            g0 += Wc[j+0] * henc[j+0];
            g1 += Wc[j+1] * henc[j+1];
            g2 += Wc[j+2] * henc[j+2];
            g3 += Wc[j+3] * henc[j+3];
        }
        float d0 = 0.f, d1 = 0.f, d2 = 0.f, d3 = 0.f;
#pragma unroll
        for (int j = 0; j < H_; j += 4) {
            d0 += Wd[j+0] * hdec[j+0];
            d1 += Wd[j+1] * hdec[j+1];
            d2 += Wd[j+2] * hdec[j+2];
            d3 += Wd[j+3] * hdec[j+3];
        }
        float d = fast_tanh(((g0 + g1) + (g2 + g3)) + ((d0 + d1) + (d2 + d3)));

        lhd[half][i] = d;
#pragma unroll
        for (int q = 0; q < H_ / 4; ++q) {
            float4 v = *reinterpret_cast<const float4*>(&lhd[half][4 * q]);
            hdec[4*q+0] = v.x; hdec[4*q+1] = v.y;
            hdec[4*q+2] = v.z; hdec[4*q+3] = v.w;
        }

        // fused readout: out[b,t,2i+{0,1}] = W_ro[2i+{0,1},:].hdec + b_ro
        if (t >= t0) {
            float s00 = bo0, s01 = 0.f, s10 = bo1, s11 = 0.f;
#pragma unroll
            for (int j = 0; j < H_; j += 2) {
                s00 += Wo0[j]     * hdec[j];
                s01 += Wo0[j + 1] * hdec[j + 1];
                s10 += Wo1[j]     * hdec[j];
                s11 += Wo1[j + 1] * hdec[j + 1];
            }
            float2 o = make_float2(s00 + s01, s10 + s11);
            *reinterpret_cast<float2*>(ob + (long)t * DIN) = o;
        }
        ucur = unext;
    }
}

extern "C" void kernel_launch(void* const* d_in, const int* in_sizes, int n_in,
                              void* d_out, int out_size, void* d_ws, size_t ws_size,
                              hipStream_t stream) {
    const float* x         = (const float*)d_in[0];
    const float* W_in      = (const float*)d_in[1];
    const float* b_in      = (const float*)d_in[2];
    const float* W_res_enc = (const float*)d_in[3];
    const float* b_res_enc = (const float*)d_in[4];
    const float* W_code    = (const float*)d_in[5];
    const float* b_code    = (const float*)d_in[6];
    const float* W_co      = (const float*)d_in[7];
    const float* b_co      = (const float*)d_in[8];
    const float* W_res_dec = (const float*)d_in[9];
    const float* b_res_dec = (const float*)d_in[10];
    const float* W_ro      = (const float*)d_in[11];
    const float* b_ro      = (const float*)d_in[12];
    float* out = (float*)d_out;

    char* ws = (char*)d_ws;
    float* W_comb = (float*)(ws + OFF_WCOMB);
    float* b_comb = (float*)(ws + OFF_BCOMB);
    float* u      = (float*)(ws + OFF_U);

    prep_kernel<<<1, 1024, 0, stream>>>(W_code, b_code, W_co, b_co, W_comb, b_comb);
    inproj_kernel<<<(B_ * T_) / 128, 256, 0, stream>>>(x, W_in, b_in, u);
    scan_kernel<<<(B_ / 2) * NCHUNK, 64, 0, stream>>>(u, W_res_enc, b_res_enc,
                                                      W_res_dec, b_res_dec,
                                                      W_comb, b_comb, W_ro, b_ro, out);
}